// Round 5
// baseline (1091.406 us; speedup 1.0000x reference)
//
#include <hip/hip_runtime.h>
#include <math.h>

#define BATCH 8
#define CCH   256
#define HH    64
#define WW    64
#define NN    4096                    // HH*WW

#define BNC   (BATCH * NN * CCH)      // 8,388,608 elems per tensor
#define WELEMS (3 * 8 * 9 * 256 * 32) // 1,769,472 fp16 weight elems per hi/lo

typedef __bf16   bf16x8 __attribute__((ext_vector_type(8)));
typedef _Float16 f16x8  __attribute__((ext_vector_type(8)));
typedef _Float16 f16x4  __attribute__((ext_vector_type(4)));
typedef float    f32x4  __attribute__((ext_vector_type(4)));

// ---------------------------------------------------------------------------
// Weights: OIHW fp32 -> fp16 hi/lo, layout [conv][cc8][tap9][co256][ci32]
// ---------------------------------------------------------------------------
__global__ void wtrans_kernel(const float* __restrict__ w1,
                              const float* __restrict__ w2,
                              const float* __restrict__ w3,
                              _Float16* __restrict__ Whi,
                              _Float16* __restrict__ Wlo) {
    int e = blockIdx.x * 256 + threadIdx.x;      // 0 .. WELEMS-1
    int t = e;
    const int ci  = t & 31;  t >>= 5;
    const int co  = t & 255; t >>= 8;
    const int tap = t % 9;   t /= 9;
    const int cc  = t & 7;   t >>= 3;
    const int conv = t;
    const float* src = (conv == 0) ? w1 : (conv == 1) ? w2 : w3;
    const float v = src[co * 2304 + (cc * 32 + ci) * 9 + tap];
    const _Float16 h = (_Float16)v;
    Whi[e] = h;
    Wlo[e] = (_Float16)(v - (float)h);
}

// ---------------------------------------------------------------------------
// X: [b][ci][h][w] fp32 -> Xhi/Xlo fp16 [b][h][w][ci]  (transpose via LDS)
// ---------------------------------------------------------------------------
__global__ __launch_bounds__(256)
void xsplit_kernel(const float* __restrict__ X,
                   _Float16* __restrict__ Xhi, _Float16* __restrict__ Xlo) {
    __shared__ float T[64][65];
    const int h = blockIdx.x, c0 = blockIdx.y * 64, bb = blockIdx.z;
    const int t = threadIdx.x;
    const int row = t >> 2, q = (t & 3) * 16;
#pragma unroll
    for (int k = 0; k < 4; ++k) {
        float4 v = *(const float4*)&X[(((size_t)bb * CCH + c0 + row) * HH + h) * WW + q + k * 4];
        *(float4*)&T[row][q + k * 4] = v;
    }
    __syncthreads();
    f16x8 h0, h1, l0, l1;
#pragma unroll
    for (int j = 0; j < 8; ++j) {
        float v = T[q + j][row];
        _Float16 hh = (_Float16)v;
        h0[j] = hh; l0[j] = (_Float16)(v - (float)hh);
    }
#pragma unroll
    for (int j = 0; j < 8; ++j) {
        float v = T[q + 8 + j][row];
        _Float16 hh = (_Float16)v;
        h1[j] = hh; l1[j] = (_Float16)(v - (float)hh);
    }
    const size_t g = (((size_t)bb * HH + h) * WW + row) * CCH + c0 + q;
    *(f16x8*)(Xhi + g) = h0;  *(f16x8*)(Xhi + g + 8) = h1;
    *(f16x8*)(Xlo + g) = l0;  *(f16x8*)(Xlo + g + 8) = l1;
}

// ---------------------------------------------------------------------------
// MFMA implicit-GEMM conv 3x3 SAME + bias (unchanged).
// ---------------------------------------------------------------------------
__global__ __launch_bounds__(512, 2)
void conv_mfma_kernel(const _Float16* __restrict__ Xhi, const _Float16* __restrict__ Xlo,
                      const _Float16* __restrict__ Whi, const _Float16* __restrict__ Wlo,
                      const float* __restrict__ b1, const float* __restrict__ b2,
                      const float* __restrict__ b3,
                      __bf16* __restrict__ Qhi, __bf16* __restrict__ Qlo,
                      __bf16* __restrict__ Khi, __bf16* __restrict__ Klo,
                      float* __restrict__ Dws) {
    const int h0   = blockIdx.x * 2;
    const int bb   = blockIdx.y;
    const int conv = blockIdx.z;
    const int tid  = threadIdx.x;
    const int wave = tid >> 6;
    const int lane = tid & 63;
    const int quad = lane >> 4;
    const int l16  = lane & 15;
    const int mg   = wave >> 2;
    const int ng   = wave & 3;

    __shared__ _Float16 XsH[4 * 64 * 32];
    __shared__ _Float16 XsL[4 * 64 * 32];
    __shared__ _Float16 WsH[256 * 32];
    __shared__ _Float16 WsL[256 * 32];

    const bool threePass = (conv < 2);
    const float* bias = (conv == 0) ? b1 : (conv == 1) ? b2 : b3;

    f32x4 acc[4][4];
#pragma unroll
    for (int j = 0; j < 4; ++j) {
        const float bv = bias[ng * 64 + j * 16 + l16];
#pragma unroll
        for (int i = 0; i < 4; ++i) acc[i][j] = (f32x4){bv, bv, bv, bv};
    }

    const f16x8 zf = {0, 0, 0, 0, 0, 0, 0, 0};
    const int xrow = tid >> 7;
    const int xw   = (tid >> 1) & 63;
    const int xch  = (tid & 1) * 16;

    for (int cc = 0; cc < 8; ++cc) {
        for (int tap = 0; tap < 9; ++tap) {
            __syncthreads();
            if (tap == 0) {
                const int h = h0 - 1 + xrow;
                f16x8 a0 = zf, a1 = zf, b0 = zf, b1v = zf;
                if ((unsigned)h < (unsigned)HH) {
                    const size_t g = (((size_t)bb * HH + h) * WW + xw) * CCH + cc * 32 + xch;
                    a0 = *(const f16x8*)(Xhi + g);  a1 = *(const f16x8*)(Xhi + g + 8);
                    b0 = *(const f16x8*)(Xlo + g);  b1v = *(const f16x8*)(Xlo + g + 8);
                }
                const int l = (xrow * 64 + xw) * 32 + xch;
                *(f16x8*)&XsH[l] = a0;  *(f16x8*)&XsH[l + 8] = a1;
                *(f16x8*)&XsL[l] = b0;  *(f16x8*)&XsL[l + 8] = b1v;
            }
            {
                const size_t g = (((size_t)conv * 8 + cc) * 9 + tap) * 8192 + tid * 16;
                *(f16x8*)&WsH[tid * 16]     = *(const f16x8*)(Whi + g);
                *(f16x8*)&WsH[tid * 16 + 8] = *(const f16x8*)(Whi + g + 8);
                if (threePass) {
                    *(f16x8*)&WsL[tid * 16]     = *(const f16x8*)(Wlo + g);
                    *(f16x8*)&WsL[tid * 16 + 8] = *(const f16x8*)(Wlo + g + 8);
                }
            }
            __syncthreads();

            const int dh = tap / 3, dw = tap % 3;
            f16x8 ah[4], al[4];
#pragma unroll
            for (int i = 0; i < 4; ++i) {
                const int col = i * 16 + l16 + dw - 1;
                const bool ok = (unsigned)col < (unsigned)WW;
                const int colc = ok ? col : 0;
                const int off = ((mg + dh) * 64 + colc) * 32 + quad * 8;
                f16x8 th = *(const f16x8*)&XsH[off];
                ah[i] = ok ? th : zf;
                if (threePass) {
                    f16x8 tl = *(const f16x8*)&XsL[off];
                    al[i] = ok ? tl : zf;
                }
            }
#pragma unroll
            for (int j = 0; j < 4; ++j) {
                const int boff = (ng * 64 + j * 16 + l16) * 32 + quad * 8;
                const f16x8 bh = *(const f16x8*)&WsH[boff];
                if (threePass) {
                    const f16x8 bl = *(const f16x8*)&WsL[boff];
#pragma unroll
                    for (int i = 0; i < 4; ++i) {
                        acc[i][j] = __builtin_amdgcn_mfma_f32_16x16x32_f16(ah[i], bh, acc[i][j], 0, 0, 0);
                        acc[i][j] = __builtin_amdgcn_mfma_f32_16x16x32_f16(al[i], bh, acc[i][j], 0, 0, 0);
                        acc[i][j] = __builtin_amdgcn_mfma_f32_16x16x32_f16(ah[i], bl, acc[i][j], 0, 0, 0);
                    }
                } else {
#pragma unroll
                    for (int i = 0; i < 4; ++i)
                        acc[i][j] = __builtin_amdgcn_mfma_f32_16x16x32_f16(ah[i], bh, acc[i][j], 0, 0, 0);
                }
            }
        }
    }

    const size_t nb = (size_t)bb * NN + (size_t)(h0 + mg) * 64;
    if (threePass) {
        __bf16* Hi = conv ? Khi : Qhi;
        __bf16* Lo = conv ? Klo : Qlo;
#pragma unroll
        for (int i = 0; i < 4; ++i) {
            const int wx0 = i * 16 + quad * 4;
#pragma unroll
            for (int j = 0; j < 4; ++j) {
                const int co = ng * 64 + j * 16 + l16;
#pragma unroll
                for (int r = 0; r < 4; ++r) {
                    const float v = acc[i][j][r];
                    const size_t idx = (nb + wx0 + r) * CCH + co;
                    const __bf16 h = (__bf16)v;
                    Hi[idx] = h;
                    Lo[idx] = (__bf16)(v - (float)h);
                }
            }
        }
    } else {
#pragma unroll
        for (int i = 0; i < 4; ++i) {
            const int wx0 = i * 16 + quad * 4;
#pragma unroll
            for (int j = 0; j < 4; ++j) {
                const int co = ng * 64 + j * 16 + l16;
#pragma unroll
                for (int r = 0; r < 4; ++r)
                    Dws[(nb + wx0 + r) * CCH + co] = acc[i][j][r];
            }
        }
    }
}

// ---------------------------------------------------------------------------
// Transpose D (fp32 [b][n][c]) -> Vt (fp16 [b][c][n]).
// ---------------------------------------------------------------------------
__global__ __launch_bounds__(256)
void transpose_v_kernel(const float* __restrict__ D, _Float16* __restrict__ Vt) {
    __shared__ float T[64][65];
    const int n0 = blockIdx.x * 64, c0 = blockIdx.y * 64, bb = blockIdx.z;
    const int t = threadIdx.x;
    const int row = t >> 2, q = (t & 3) * 16;
#pragma unroll
    for (int k = 0; k < 4; ++k) {
        float4 v = *(const float4*)(D + ((size_t)bb * NN + n0 + row) * CCH + c0 + q + k * 4);
        *(float4*)&T[row][q + k * 4] = v;
    }
    __syncthreads();
    f16x8 o0, o1;
#pragma unroll
    for (int j = 0; j < 8; ++j) o0[j] = (_Float16)T[q + j][row];
#pragma unroll
    for (int j = 0; j < 8; ++j) o1[j] = (_Float16)T[q + 8 + j][row];
    _Float16* dst = Vt + ((size_t)bb * CCH + c0 + row) * NN + n0 + q;
    *(f16x8*)dst = o0;
    *(f16x8*)(dst + 8) = o1;
}

// ---------------------------------------------------------------------------
// MFMA flash attention v4: kv-split x2 (flash-decoding), 4 waves x 32 q-rows.
// Grid 512 = (half, qb, bb) -> 2 blocks/CU, 2 waves/SIMD for latency hiding.
// Each block: 32 kv-tiles, emits unnormalized O-partial + (m,l) per q.
// LDS tiles XOR-swizzled on 16B units (u ^= row&7): K [64][128] and
// V [256][64] (union, 32 KB) + per-wave P [32][72] (18 KB) = 50 KB.
// ---------------------------------------------------------------------------
__global__ __launch_bounds__(256, 2)
void attn_mfma_kernel(const __bf16* __restrict__ Qhi, const __bf16* __restrict__ Qlo,
                      const __bf16* __restrict__ Khi, const __bf16* __restrict__ Klo,
                      const _Float16* __restrict__ Vt,
                      float* __restrict__ O0, float* __restrict__ O1,
                      float* __restrict__ Ml) {
    const int blk  = blockIdx.x;
    const int bb   = blk & 7;          // batch -> XCD
    const int qb   = (blk >> 3) & 31;
    const int half = blk >> 8;
    const int n0 = qb * 128;
    const int tid  = threadIdx.x;
    const int wave = tid >> 6;         // 0..3
    const int lane = tid & 63;
    const int quad = lane >> 4;
    const int l16  = lane & 15;
    const int xq   = l16 & 7;          // swizzle key for frag reads

    __shared__ __align__(16) unsigned char smem[32768 + 4 * 32 * 72 * 2];
    __bf16*   KsHi = (__bf16*)smem;                    // [64][128] swizzled
    __bf16*   KsLo = KsHi + 64 * 128;
    _Float16* Vs   = (_Float16*)smem;                  // [256][64] swizzled (overlay)
    _Float16* Pw   = (_Float16*)(smem + 32768) + wave * 32 * 72;  // [32][72]

    // Q resident in registers as B-frags
    bf16x8 qh[2][8], ql[2][8];
#pragma unroll
    for (int qt = 0; qt < 2; ++qt) {
        const size_t base = ((size_t)bb * NN + n0 + wave * 32 + qt * 16 + l16) * CCH + quad * 8;
#pragma unroll
        for (int ks = 0; ks < 8; ++ks) {
            qh[qt][ks] = *(const bf16x8*)(Qhi + base + ks * 32);
            ql[qt][ks] = *(const bf16x8*)(Qlo + base + ks * 32);
        }
    }

    f32x4 Oacc[16][2];    // [cf][qt]
#pragma unroll
    for (int cf = 0; cf < 16; ++cf)
#pragma unroll
        for (int qt = 0; qt < 2; ++qt) Oacc[cf][qt] = (f32x4){0.f, 0.f, 0.f, 0.f};
    float m_i[2], l_i[2];
#pragma unroll
    for (int qt = 0; qt < 2; ++qt) { m_i[qt] = -INFINITY; l_i[qt] = 0.f; }

    const int krow = tid >> 2, part = tid & 3;

    for (int t = 0; t < 32; ++t) {
        const int m0 = (half * 32 + t) * 64;
        f32x4 Sacc[4][2];   // [kvt][qt]
#pragma unroll
        for (int kvt = 0; kvt < 4; ++kvt)
#pragma unroll
            for (int qt = 0; qt < 2; ++qt) Sacc[kvt][qt] = (f32x4){0.f, 0.f, 0.f, 0.f};

        // ---- S^T = K Q^T : two 128-channel chunks through LDS ----
        for (int cc = 0; cc < 2; ++cc) {
            __syncthreads();
#pragma unroll
            for (int i = 0; i < 4; ++i) {
                const int u = part * 4 + i;
                const size_t g = ((size_t)bb * NN + m0 + krow) * CCH + cc * 128 + u * 8;
                const int lo = krow * 128 + ((u ^ (krow & 7)) * 8);
                *(bf16x8*)&KsHi[lo] = *(const bf16x8*)(Khi + g);
                *(bf16x8*)&KsLo[lo] = *(const bf16x8*)(Klo + g);
            }
            __syncthreads();
#pragma unroll
            for (int ks = 0; ks < 4; ++ks) {
#pragma unroll
                for (int kvt = 0; kvt < 4; ++kvt) {
                    const int off = (kvt * 16 + l16) * 128 + (((ks * 4 + quad) ^ xq) * 8);
                    const bf16x8 kh = *(const bf16x8*)&KsHi[off];
                    const bf16x8 kl = *(const bf16x8*)&KsLo[off];
                    const int kq = cc * 4 + ks;
                    Sacc[kvt][0] = __builtin_amdgcn_mfma_f32_16x16x32_bf16(kh, qh[0][kq], Sacc[kvt][0], 0, 0, 0);
                    Sacc[kvt][1] = __builtin_amdgcn_mfma_f32_16x16x32_bf16(kh, qh[1][kq], Sacc[kvt][1], 0, 0, 0);
                    Sacc[kvt][0] = __builtin_amdgcn_mfma_f32_16x16x32_bf16(kh, ql[0][kq], Sacc[kvt][0], 0, 0, 0);
                    Sacc[kvt][1] = __builtin_amdgcn_mfma_f32_16x16x32_bf16(kh, ql[1][kq], Sacc[kvt][1], 0, 0, 0);
                    Sacc[kvt][0] = __builtin_amdgcn_mfma_f32_16x16x32_bf16(kl, qh[0][kq], Sacc[kvt][0], 0, 0, 0);
                    Sacc[kvt][1] = __builtin_amdgcn_mfma_f32_16x16x32_bf16(kl, qh[1][kq], Sacc[kvt][1], 0, 0, 0);
                }
            }
        }

        // ---- online softmax ----
        float scale[2];
#pragma unroll
        for (int qt = 0; qt < 2; ++qt) {
            float mx = -INFINITY;
#pragma unroll
            for (int kvt = 0; kvt < 4; ++kvt)
#pragma unroll
                for (int r = 0; r < 4; ++r) mx = fmaxf(mx, Sacc[kvt][qt][r]);
            mx = fmaxf(mx, __shfl_xor(mx, 16, 64));
            mx = fmaxf(mx, __shfl_xor(mx, 32, 64));
            const float mnew = fmaxf(m_i[qt], mx);
            float rs = 0.f;
#pragma unroll
            for (int kvt = 0; kvt < 4; ++kvt) {
                f16x4 pw;
#pragma unroll
                for (int r = 0; r < 4; ++r) {
                    const float p = __expf(Sacc[kvt][qt][r] - mnew);
                    rs += p;
                    pw[r] = (_Float16)p;
                }
                *(f16x4*)&Pw[(qt * 16 + l16) * 72 + kvt * 16 + quad * 4] = pw;
            }
            rs += __shfl_xor(rs, 16, 64);
            rs += __shfl_xor(rs, 32, 64);
            scale[qt] = __expf(m_i[qt] - mnew);    // 0 on first tile
            l_i[qt] = l_i[qt] * scale[qt] + rs;
            m_i[qt] = mnew;
        }
#pragma unroll
        for (int cf = 0; cf < 16; ++cf)
#pragma unroll
            for (int qt = 0; qt < 2; ++qt) {
                Oacc[cf][qt][0] *= scale[qt];
                Oacc[cf][qt][1] *= scale[qt];
                Oacc[cf][qt][2] *= scale[qt];
                Oacc[cf][qt][3] *= scale[qt];
            }

        // ---- stage V tile [256 c][64 kv] (region reuse after S-phase) ----
        __syncthreads();
#pragma unroll
        for (int i = 0; i < 8; ++i) {
            const size_t g = ((size_t)bb * CCH + tid) * NN + m0 + i * 8;
            *(f16x8*)&Vs[tid * 64 + ((i ^ (tid & 7)) * 8)] = *(const f16x8*)(Vt + g);
        }
        __syncthreads();

        // ---- O^T += V^T P^T ----
        f16x8 pf[2][2];
#pragma unroll
        for (int qt = 0; qt < 2; ++qt)
#pragma unroll
            for (int kvf = 0; kvf < 2; ++kvf)
                pf[qt][kvf] = *(const f16x8*)&Pw[(qt * 16 + l16) * 72 + kvf * 32 + quad * 8];
#pragma unroll
        for (int cf = 0; cf < 16; ++cf) {
#pragma unroll
            for (int kvf = 0; kvf < 2; ++kvf) {
                const f16x8 vf = *(const f16x8*)&Vs[(cf * 16 + l16) * 64 + (((kvf * 4 + quad) ^ xq) * 8)];
                Oacc[cf][0] = __builtin_amdgcn_mfma_f32_16x16x32_f16(vf, pf[0][kvf], Oacc[cf][0], 0, 0, 0);
                Oacc[cf][1] = __builtin_amdgcn_mfma_f32_16x16x32_f16(vf, pf[1][kvf], Oacc[cf][1], 0, 0, 0);
            }
        }
    }

    // ---- epilogue: raw partial O, plus (m,l) per q ----
    float* Op = half ? O1 : O0;
#pragma unroll
    for (int cf = 0; cf < 16; ++cf) {
#pragma unroll
        for (int qt = 0; qt < 2; ++qt) {
            const int qg = n0 + wave * 32 + qt * 16 + l16;
#pragma unroll
            for (int r = 0; r < 4; ++r) {
                const int c = cf * 16 + quad * 4 + r;
                Op[((size_t)bb * CCH + c) * NN + qg] = Oacc[cf][qt][r];
            }
        }
    }
    if (quad == 0) {
#pragma unroll
        for (int qt = 0; qt < 2; ++qt) {
            const int qg = n0 + wave * 32 + qt * 16 + l16;
            Ml[(((size_t)half * BATCH + bb) * 2 + 0) * NN + qg] = m_i[qt];
            Ml[(((size_t)half * BATCH + bb) * 2 + 1) * NN + qg] = l_i[qt];
        }
    }
}

// ---------------------------------------------------------------------------
// Combine the two kv-half partials: out = alpha*(O0*w0+O1*w1)/(l0*w0+l1*w1).
// ---------------------------------------------------------------------------
__global__ __launch_bounds__(256)
void combine_kernel(const float* __restrict__ O0, const float* __restrict__ O1,
                    const float* __restrict__ Ml, const float* __restrict__ alpha_p,
                    float* __restrict__ out) {
    const int n  = blockIdx.x * 256 + threadIdx.x;   // grid.x = 16
    const int c0 = blockIdx.y * 64;                  // grid.y = 4
    const int bb = blockIdx.z;
    const float m0v = Ml[(((size_t)0 * BATCH + bb) * 2 + 0) * NN + n];
    const float l0v = Ml[(((size_t)0 * BATCH + bb) * 2 + 1) * NN + n];
    const float m1v = Ml[(((size_t)1 * BATCH + bb) * 2 + 0) * NN + n];
    const float l1v = Ml[(((size_t)1 * BATCH + bb) * 2 + 1) * NN + n];
    const float M  = fmaxf(m0v, m1v);
    const float w0 = __expf(m0v - M), w1 = __expf(m1v - M);
    const float inv = (*alpha_p) / (l0v * w0 + l1v * w1);
    const float a0 = w0 * inv, a1 = w1 * inv;
#pragma unroll 4
    for (int c = c0; c < c0 + 64; ++c) {
        const size_t idx = ((size_t)bb * CCH + c) * NN + n;
        out[idx] = O0[idx] * a0 + O1[idx] * a1;
    }
}

// ---------------------------------------------------------------------------
extern "C" void kernel_launch(void* const* d_in, const int* in_sizes, int n_in,
                              void* d_out, int out_size, void* d_ws, size_t ws_size,
                              hipStream_t stream) {
    const float* X  = (const float*)d_in[0];
    const float* w1 = (const float*)d_in[1];
    const float* b1 = (const float*)d_in[2];
    const float* w2 = (const float*)d_in[3];
    const float* b2 = (const float*)d_in[4];
    const float* w3 = (const float*)d_in[5];
    const float* b3 = (const float*)d_in[6];
    const float* alpha = (const float*)d_in[7];
    float* out = (float*)d_out;

    float*    Dws = (float*)d_ws;                 // fp32 BNC; dead after transpose_v
    __bf16*   Qhi = (__bf16*)(Dws + (size_t)BNC);
    __bf16*   Qlo = Qhi + (size_t)BNC;
    __bf16*   Khi = Qlo + (size_t)BNC;
    __bf16*   Klo = Khi + (size_t)BNC;
    _Float16* Vt  = (_Float16*)(Klo + (size_t)BNC);
    _Float16* Xhi = Vt + (size_t)BNC;             // dead after conv
    _Float16* Xlo = Xhi + (size_t)BNC;            // dead after conv
    _Float16* Whi = Xlo + (size_t)BNC;
    _Float16* Wlo = Whi + (size_t)WELEMS;         // dead after conv

    // overlays (live only during attention+combine)
    float* O0 = Dws;                              // BNC fp32
    float* O1 = (float*)Xhi;                      // 2*BNC f16 bytes = BNC fp32
    float* Ml = (float*)Wlo;                      // 128K floats < WELEMS f16 bytes

    wtrans_kernel<<<dim3(WELEMS / 256), 256, 0, stream>>>(w1, w2, w3, Whi, Wlo);

    xsplit_kernel<<<dim3(HH, CCH / 64, BATCH), 256, 0, stream>>>(X, Xhi, Xlo);

    conv_mfma_kernel<<<dim3(HH / 2, BATCH, 3), 512, 0, stream>>>(
        Xhi, Xlo, Whi, Wlo, b1, b2, b3, Qhi, Qlo, Khi, Klo, Dws);

    transpose_v_kernel<<<dim3(NN / 64, CCH / 64, BATCH), 256, 0, stream>>>(Dws, Vt);

    attn_mfma_kernel<<<dim3(512), 256, 0, stream>>>(Qhi, Qlo, Khi, Klo, Vt, O0, O1, Ml);

    combine_kernel<<<dim3(NN / 256, 4, BATCH), 256, 0, stream>>>(O0, O1, Ml, alpha, out);
}

// Round 6
// 942.474 us; speedup vs baseline: 1.1580x; 1.1580x over previous
//
#include <hip/hip_runtime.h>
#include <math.h>

#define BATCH 8
#define CCH   256
#define HH    64
#define WW    64
#define NN    4096                    // HH*WW

#define BNC   (BATCH * NN * CCH)      // 8,388,608 elems per tensor
#define WELEMS (3 * 8 * 9 * 256 * 32) // 1,769,472 fp16 weight elems per hi/lo

typedef __bf16   bf16x8 __attribute__((ext_vector_type(8)));
typedef _Float16 f16x8  __attribute__((ext_vector_type(8)));
typedef _Float16 f16x4  __attribute__((ext_vector_type(4)));
typedef float    f32x4  __attribute__((ext_vector_type(4)));

// ---------------------------------------------------------------------------
// Weights: OIHW fp32 -> fp16 hi/lo, layout [conv][cc8][tap9][co256][ci32]
// ---------------------------------------------------------------------------
__global__ void wtrans_kernel(const float* __restrict__ w1,
                              const float* __restrict__ w2,
                              const float* __restrict__ w3,
                              _Float16* __restrict__ Whi,
                              _Float16* __restrict__ Wlo) {
    int e = blockIdx.x * 256 + threadIdx.x;      // 0 .. WELEMS-1
    int t = e;
    const int ci  = t & 31;  t >>= 5;
    const int co  = t & 255; t >>= 8;
    const int tap = t % 9;   t /= 9;
    const int cc  = t & 7;   t >>= 3;
    const int conv = t;
    const float* src = (conv == 0) ? w1 : (conv == 1) ? w2 : w3;
    const float v = src[co * 2304 + (cc * 32 + ci) * 9 + tap];
    const _Float16 h = (_Float16)v;
    Whi[e] = h;
    Wlo[e] = (_Float16)(v - (float)h);
}

// ---------------------------------------------------------------------------
// X: [b][ci][h][w] fp32 -> Xhi/Xlo fp16 [b][h][w][ci]  (transpose via LDS)
// ---------------------------------------------------------------------------
__global__ __launch_bounds__(256)
void xsplit_kernel(const float* __restrict__ X,
                   _Float16* __restrict__ Xhi, _Float16* __restrict__ Xlo) {
    __shared__ float T[64][65];
    const int h = blockIdx.x, c0 = blockIdx.y * 64, bb = blockIdx.z;
    const int t = threadIdx.x;
    const int row = t >> 2, q = (t & 3) * 16;
#pragma unroll
    for (int k = 0; k < 4; ++k) {
        float4 v = *(const float4*)&X[(((size_t)bb * CCH + c0 + row) * HH + h) * WW + q + k * 4];
        *(float4*)&T[row][q + k * 4] = v;
    }
    __syncthreads();
    f16x8 h0, h1, l0, l1;
#pragma unroll
    for (int j = 0; j < 8; ++j) {
        float v = T[q + j][row];
        _Float16 hh = (_Float16)v;
        h0[j] = hh; l0[j] = (_Float16)(v - (float)hh);
    }
#pragma unroll
    for (int j = 0; j < 8; ++j) {
        float v = T[q + 8 + j][row];
        _Float16 hh = (_Float16)v;
        h1[j] = hh; l1[j] = (_Float16)(v - (float)hh);
    }
    const size_t g = (((size_t)bb * HH + h) * WW + row) * CCH + c0 + q;
    *(f16x8*)(Xhi + g) = h0;  *(f16x8*)(Xhi + g + 8) = h1;
    *(f16x8*)(Xlo + g) = l0;  *(f16x8*)(Xlo + g + 8) = l1;
}

// ---------------------------------------------------------------------------
// MFMA implicit-GEMM conv 3x3 SAME + bias (unchanged).
// ---------------------------------------------------------------------------
__global__ __launch_bounds__(512, 2)
void conv_mfma_kernel(const _Float16* __restrict__ Xhi, const _Float16* __restrict__ Xlo,
                      const _Float16* __restrict__ Whi, const _Float16* __restrict__ Wlo,
                      const float* __restrict__ b1, const float* __restrict__ b2,
                      const float* __restrict__ b3,
                      __bf16* __restrict__ Qhi, __bf16* __restrict__ Qlo,
                      __bf16* __restrict__ Khi, __bf16* __restrict__ Klo,
                      float* __restrict__ Dws) {
    const int h0   = blockIdx.x * 2;
    const int bb   = blockIdx.y;
    const int conv = blockIdx.z;
    const int tid  = threadIdx.x;
    const int wave = tid >> 6;
    const int lane = tid & 63;
    const int quad = lane >> 4;
    const int l16  = lane & 15;
    const int mg   = wave >> 2;
    const int ng   = wave & 3;

    __shared__ _Float16 XsH[4 * 64 * 32];
    __shared__ _Float16 XsL[4 * 64 * 32];
    __shared__ _Float16 WsH[256 * 32];
    __shared__ _Float16 WsL[256 * 32];

    const bool threePass = (conv < 2);
    const float* bias = (conv == 0) ? b1 : (conv == 1) ? b2 : b3;

    f32x4 acc[4][4];
#pragma unroll
    for (int j = 0; j < 4; ++j) {
        const float bv = bias[ng * 64 + j * 16 + l16];
#pragma unroll
        for (int i = 0; i < 4; ++i) acc[i][j] = (f32x4){bv, bv, bv, bv};
    }

    const f16x8 zf = {0, 0, 0, 0, 0, 0, 0, 0};
    const int xrow = tid >> 7;
    const int xw   = (tid >> 1) & 63;
    const int xch  = (tid & 1) * 16;

    for (int cc = 0; cc < 8; ++cc) {
        for (int tap = 0; tap < 9; ++tap) {
            __syncthreads();
            if (tap == 0) {
                const int h = h0 - 1 + xrow;
                f16x8 a0 = zf, a1 = zf, b0 = zf, b1v = zf;
                if ((unsigned)h < (unsigned)HH) {
                    const size_t g = (((size_t)bb * HH + h) * WW + xw) * CCH + cc * 32 + xch;
                    a0 = *(const f16x8*)(Xhi + g);  a1 = *(const f16x8*)(Xhi + g + 8);
                    b0 = *(const f16x8*)(Xlo + g);  b1v = *(const f16x8*)(Xlo + g + 8);
                }
                const int l = (xrow * 64 + xw) * 32 + xch;
                *(f16x8*)&XsH[l] = a0;  *(f16x8*)&XsH[l + 8] = a1;
                *(f16x8*)&XsL[l] = b0;  *(f16x8*)&XsL[l + 8] = b1v;
            }
            {
                const size_t g = (((size_t)conv * 8 + cc) * 9 + tap) * 8192 + tid * 16;
                *(f16x8*)&WsH[tid * 16]     = *(const f16x8*)(Whi + g);
                *(f16x8*)&WsH[tid * 16 + 8] = *(const f16x8*)(Whi + g + 8);
                if (threePass) {
                    *(f16x8*)&WsL[tid * 16]     = *(const f16x8*)(Wlo + g);
                    *(f16x8*)&WsL[tid * 16 + 8] = *(const f16x8*)(Wlo + g + 8);
                }
            }
            __syncthreads();

            const int dh = tap / 3, dw = tap % 3;
            f16x8 ah[4], al[4];
#pragma unroll
            for (int i = 0; i < 4; ++i) {
                const int col = i * 16 + l16 + dw - 1;
                const bool ok = (unsigned)col < (unsigned)WW;
                const int colc = ok ? col : 0;
                const int off = ((mg + dh) * 64 + colc) * 32 + quad * 8;
                f16x8 th = *(const f16x8*)&XsH[off];
                ah[i] = ok ? th : zf;
                if (threePass) {
                    f16x8 tl = *(const f16x8*)&XsL[off];
                    al[i] = ok ? tl : zf;
                }
            }
#pragma unroll
            for (int j = 0; j < 4; ++j) {
                const int boff = (ng * 64 + j * 16 + l16) * 32 + quad * 8;
                const f16x8 bh = *(const f16x8*)&WsH[boff];
                if (threePass) {
                    const f16x8 bl = *(const f16x8*)&WsL[boff];
#pragma unroll
                    for (int i = 0; i < 4; ++i) {
                        acc[i][j] = __builtin_amdgcn_mfma_f32_16x16x32_f16(ah[i], bh, acc[i][j], 0, 0, 0);
                        acc[i][j] = __builtin_amdgcn_mfma_f32_16x16x32_f16(al[i], bh, acc[i][j], 0, 0, 0);
                        acc[i][j] = __builtin_amdgcn_mfma_f32_16x16x32_f16(ah[i], bl, acc[i][j], 0, 0, 0);
                    }
                } else {
#pragma unroll
                    for (int i = 0; i < 4; ++i)
                        acc[i][j] = __builtin_amdgcn_mfma_f32_16x16x32_f16(ah[i], bh, acc[i][j], 0, 0, 0);
                }
            }
        }
    }

    const size_t nb = (size_t)bb * NN + (size_t)(h0 + mg) * 64;
    if (threePass) {
        __bf16* Hi = conv ? Khi : Qhi;
        __bf16* Lo = conv ? Klo : Qlo;
#pragma unroll
        for (int i = 0; i < 4; ++i) {
            const int wx0 = i * 16 + quad * 4;
#pragma unroll
            for (int j = 0; j < 4; ++j) {
                const int co = ng * 64 + j * 16 + l16;
#pragma unroll
                for (int r = 0; r < 4; ++r) {
                    const float v = acc[i][j][r];
                    const size_t idx = (nb + wx0 + r) * CCH + co;
                    const __bf16 h = (__bf16)v;
                    Hi[idx] = h;
                    Lo[idx] = (__bf16)(v - (float)h);
                }
            }
        }
    } else {
#pragma unroll
        for (int i = 0; i < 4; ++i) {
            const int wx0 = i * 16 + quad * 4;
#pragma unroll
            for (int j = 0; j < 4; ++j) {
                const int co = ng * 64 + j * 16 + l16;
#pragma unroll
                for (int r = 0; r < 4; ++r)
                    Dws[(nb + wx0 + r) * CCH + co] = acc[i][j][r];
            }
        }
    }
}

// ---------------------------------------------------------------------------
// Transpose D (fp32 [b][n][c]) -> Vt (fp16 [b][c][n]).
// ---------------------------------------------------------------------------
__global__ __launch_bounds__(256)
void transpose_v_kernel(const float* __restrict__ D, _Float16* __restrict__ Vt) {
    __shared__ float T[64][65];
    const int n0 = blockIdx.x * 64, c0 = blockIdx.y * 64, bb = blockIdx.z;
    const int t = threadIdx.x;
    const int row = t >> 2, q = (t & 3) * 16;
#pragma unroll
    for (int k = 0; k < 4; ++k) {
        float4 v = *(const float4*)(D + ((size_t)bb * NN + n0 + row) * CCH + c0 + q + k * 4);
        *(float4*)&T[row][q + k * 4] = v;
    }
    __syncthreads();
    f16x8 o0, o1;
#pragma unroll
    for (int j = 0; j < 8; ++j) o0[j] = (_Float16)T[q + j][row];
#pragma unroll
    for (int j = 0; j < 8; ++j) o1[j] = (_Float16)T[q + 8 + j][row];
    _Float16* dst = Vt + ((size_t)bb * CCH + c0 + row) * NN + n0 + q;
    *(f16x8*)dst = o0;
    *(f16x8*)(dst + 8) = o1;
}

// ---------------------------------------------------------------------------
// MFMA flash attention v5: single pass (no kv-split), 4 waves x 32 q-rows,
// S^T formulation, 128-kv rounds, register-prefetch software pipelining:
//   - K staged in 64-ch chunks [128 kv][64 ch] hi/lo; chunk cc+1's global
//     loads are issued before chunk cc's MFMA (latency hidden by ~1900 cyc).
//   - V [256 c][128 kv] prefetched in 2 halves during S3 / softmax.
//   - next tile's K chunk0 prefetched during PV MFMA.
// 128-kv softmax rounds halve rescale/exp/barrier overhead vs 64-kv.
// All LDS tiles XOR-swizzled on 16B units. Dynamic LDS 130 KB, 1 block/CU,
// grid 256, batch = blockIdx&7 pins batch -> XCD.
// ---------------------------------------------------------------------------
__global__ __launch_bounds__(256, 1)
void attn_mfma_kernel(const __bf16* __restrict__ Qhi, const __bf16* __restrict__ Qlo,
                      const __bf16* __restrict__ Khi, const __bf16* __restrict__ Klo,
                      const _Float16* __restrict__ Vt, const float* __restrict__ alpha_p,
                      float* __restrict__ out) {
    const int bb = blockIdx.x & 7;     // batch -> XCD
    const int qb = blockIdx.x >> 3;    // 0..31
    const int n0 = qb * 128;
    const int tid  = threadIdx.x;
    const int wave = tid >> 6;         // 0..3
    const int lane = tid & 63;
    const int quad = lane >> 4;
    const int l16  = lane & 15;
    const int xq   = l16 & 7;

    extern __shared__ __align__(16) unsigned char smem[];
    __bf16*   KsHi = (__bf16*)(smem);                 // [128][64] swizzled
    __bf16*   KsLo = (__bf16*)(smem + 16384);         // [128][64] swizzled
    _Float16* Vs   = (_Float16*)(smem + 32768);       // [256][128] swizzled
    _Float16* Pw   = (_Float16*)(smem + 98304) + wave * 32 * 136;  // [32][136]

    // Q resident in registers as B-frags (AGPR-eligible on gfx950)
    bf16x8 qh[2][8], ql[2][8];
#pragma unroll
    for (int qt = 0; qt < 2; ++qt) {
        const size_t base = ((size_t)bb * NN + n0 + wave * 32 + qt * 16 + l16) * CCH + quad * 8;
#pragma unroll
        for (int ks = 0; ks < 8; ++ks) {
            qh[qt][ks] = *(const bf16x8*)(Qhi + base + ks * 32);
            ql[qt][ks] = *(const bf16x8*)(Qlo + base + ks * 32);
        }
    }

    f32x4 Oacc[16][2];    // [cf][qt]: O^T c=cf*16+quad*4+r, q=qt*16+l16
#pragma unroll
    for (int cf = 0; cf < 16; ++cf)
#pragma unroll
        for (int qt = 0; qt < 2; ++qt) Oacc[cf][qt] = (f32x4){0.f, 0.f, 0.f, 0.f};
    float m_i[2], l_i[2];
#pragma unroll
    for (int qt = 0; qt < 2; ++qt) { m_i[qt] = -INFINITY; l_i[qt] = 0.f; }

    // staging coords: K: 2 thr/row (128 rows), 4x16B units each per hi/lo
    const int krow = tid >> 1, khalf = tid & 1;

    bf16x8 kph[4], kpl[4];     // K-chunk prefetch regs
    f16x8  vp[8];              // V half prefetch regs

    auto kload = [&](int m0_, int cc_) {
#pragma unroll
        for (int i = 0; i < 4; ++i) {
            const int u = khalf * 4 + i;
            const size_t g = ((size_t)bb * NN + m0_ + krow) * CCH + cc_ * 64 + u * 8;
            kph[i] = *(const bf16x8*)(Khi + g);
            kpl[i] = *(const bf16x8*)(Klo + g);
        }
    };
    auto kwrite = [&]() {
#pragma unroll
        for (int i = 0; i < 4; ++i) {
            const int u = khalf * 4 + i;
            const int lo = krow * 64 + ((u ^ (krow & 7)) * 8);
            *(bf16x8*)&KsHi[lo] = kph[i];
            *(bf16x8*)&KsLo[lo] = kpl[i];
        }
    };
    auto vload = [&](int m0_, int grp) {
#pragma unroll
        for (int i = 0; i < 8; ++i) {
            const int u = grp * 8 + i;
            vp[i] = *(const f16x8*)(Vt + ((size_t)bb * CCH + tid) * NN + m0_ + u * 8);
        }
    };
    auto vwrite = [&](int grp) {
#pragma unroll
        for (int i = 0; i < 8; ++i) {
            const int u = grp * 8 + i;
            *(f16x8*)&Vs[tid * 128 + ((u ^ (tid & 7)) * 8)] = vp[i];
        }
    };

    f32x4 Sacc[8][2];
    auto schunk = [&](int cc) {
#pragma unroll
        for (int ks = 0; ks < 2; ++ks) {
            const int kq = cc * 2 + ks;
#pragma unroll
            for (int kvt = 0; kvt < 8; ++kvt) {
                const int off = (kvt * 16 + l16) * 64 + (((ks * 4 + quad) ^ xq) * 8);
                const bf16x8 kh = *(const bf16x8*)&KsHi[off];
                const bf16x8 kl = *(const bf16x8*)&KsLo[off];
                Sacc[kvt][0] = __builtin_amdgcn_mfma_f32_16x16x32_bf16(kh, qh[0][kq], Sacc[kvt][0], 0, 0, 0);
                Sacc[kvt][1] = __builtin_amdgcn_mfma_f32_16x16x32_bf16(kh, qh[1][kq], Sacc[kvt][1], 0, 0, 0);
                Sacc[kvt][0] = __builtin_amdgcn_mfma_f32_16x16x32_bf16(kl, qh[0][kq], Sacc[kvt][0], 0, 0, 0);
                Sacc[kvt][1] = __builtin_amdgcn_mfma_f32_16x16x32_bf16(kl, qh[1][kq], Sacc[kvt][1], 0, 0, 0);
                Sacc[kvt][0] = __builtin_amdgcn_mfma_f32_16x16x32_bf16(kh, ql[0][kq], Sacc[kvt][0], 0, 0, 0);
                Sacc[kvt][1] = __builtin_amdgcn_mfma_f32_16x16x32_bf16(kh, ql[1][kq], Sacc[kvt][1], 0, 0, 0);
            }
        }
    };

    // prologue: stage K chunk0 of tile 0
    kload(0, 0);
    kwrite();
    __syncthreads();

    for (int t = 0; t < 32; ++t) {
        const int m0 = t * 128;
#pragma unroll
        for (int kvt = 0; kvt < 8; ++kvt)
#pragma unroll
            for (int qt = 0; qt < 2; ++qt) Sacc[kvt][qt] = (f32x4){0.f, 0.f, 0.f, 0.f};

        // ---- S chunks 0..2 with chunk c+1 prefetch ----
        for (int cc = 0; cc < 3; ++cc) {
            kload(m0, cc + 1);
            schunk(cc);
            __syncthreads();          // all waves done reading chunk cc
            kwrite();
            __syncthreads();          // chunk cc+1 visible
        }

        // ---- S chunk 3; V prefetched in two halves ----
        vload(m0, 0);
        schunk(3);
        vwrite(0);                    // V region safe: last read before tile start
        vload(m0, 1);

        // ---- online softmax over 128 kv ----
        float scale[2];
#pragma unroll
        for (int qt = 0; qt < 2; ++qt) {
            float mx = -INFINITY;
#pragma unroll
            for (int kvt = 0; kvt < 8; ++kvt)
#pragma unroll
                for (int r = 0; r < 4; ++r) mx = fmaxf(mx, Sacc[kvt][qt][r]);
            mx = fmaxf(mx, __shfl_xor(mx, 16, 64));
            mx = fmaxf(mx, __shfl_xor(mx, 32, 64));
            const float mnew = fmaxf(m_i[qt], mx);
            float rs = 0.f;
#pragma unroll
            for (int kvt = 0; kvt < 8; ++kvt) {
                f16x4 pw;
#pragma unroll
                for (int r = 0; r < 4; ++r) {
                    const float p = __expf(Sacc[kvt][qt][r] - mnew);
                    rs += p;
                    pw[r] = (_Float16)p;
                }
                *(f16x4*)&Pw[(qt * 16 + l16) * 136 + kvt * 16 + quad * 4] = pw;
            }
            rs += __shfl_xor(rs, 16, 64);
            rs += __shfl_xor(rs, 32, 64);
            scale[qt] = __expf(m_i[qt] - mnew);    // 0 on first tile
            l_i[qt] = l_i[qt] * scale[qt] + rs;
            m_i[qt] = mnew;
        }
#pragma unroll
        for (int cf = 0; cf < 16; ++cf)
#pragma unroll
            for (int qt = 0; qt < 2; ++qt) {
                Oacc[cf][qt][0] *= scale[qt];
                Oacc[cf][qt][1] *= scale[qt];
                Oacc[cf][qt][2] *= scale[qt];
                Oacc[cf][qt][3] *= scale[qt];
            }
        vwrite(1);
        __syncthreads();              // V visible; all waves past chunk3 reads

        // ---- O^T += V^T P^T; prefetch next tile's K chunk0 ----
        kload((t == 31) ? 0 : m0 + 128, 0);
        f16x8 pf[2][4];
#pragma unroll
        for (int qt = 0; qt < 2; ++qt)
#pragma unroll
            for (int kvf = 0; kvf < 4; ++kvf)
                pf[qt][kvf] = *(const f16x8*)&Pw[(qt * 16 + l16) * 136 + kvf * 32 + quad * 8];
#pragma unroll
        for (int cf = 0; cf < 16; ++cf) {
#pragma unroll
            for (int kvf = 0; kvf < 4; ++kvf) {
                const f16x8 vf = *(const f16x8*)&Vs[(cf * 16 + l16) * 128 + (((kvf * 4 + quad) ^ xq) * 8)];
                Oacc[cf][0] = __builtin_amdgcn_mfma_f32_16x16x32_f16(vf, pf[0][kvf], Oacc[cf][0], 0, 0, 0);
                Oacc[cf][1] = __builtin_amdgcn_mfma_f32_16x16x32_f16(vf, pf[1][kvf], Oacc[cf][1], 0, 0, 0);
            }
        }
        kwrite();                     // K buffer safe: chunk3 reads ended pre-barrier
        __syncthreads();              // chunk0(t+1) visible; V reads done
    }

    // ---- epilogue: /l, *alpha, write out[b][c][n] ----
    const float alpha = *alpha_p;
    float inv[2];
#pragma unroll
    for (int qt = 0; qt < 2; ++qt) inv[qt] = alpha / l_i[qt];
#pragma unroll
    for (int cf = 0; cf < 16; ++cf) {
#pragma unroll
        for (int qt = 0; qt < 2; ++qt) {
            const int qg = n0 + wave * 32 + qt * 16 + l16;
#pragma unroll
            for (int r = 0; r < 4; ++r) {
                const int c = cf * 16 + quad * 4 + r;
                out[((size_t)bb * CCH + c) * NN + qg] = Oacc[cf][qt][r] * inv[qt];
            }
        }
    }
}

// ---------------------------------------------------------------------------
extern "C" void kernel_launch(void* const* d_in, const int* in_sizes, int n_in,
                              void* d_out, int out_size, void* d_ws, size_t ws_size,
                              hipStream_t stream) {
    const float* X  = (const float*)d_in[0];
    const float* w1 = (const float*)d_in[1];
    const float* b1 = (const float*)d_in[2];
    const float* w2 = (const float*)d_in[3];
    const float* b2 = (const float*)d_in[4];
    const float* w3 = (const float*)d_in[5];
    const float* b3 = (const float*)d_in[6];
    const float* alpha = (const float*)d_in[7];
    float* out = (float*)d_out;

    float*    Dws = (float*)d_ws;
    __bf16*   Qhi = (__bf16*)(Dws + (size_t)BNC);
    __bf16*   Qlo = Qhi + (size_t)BNC;
    __bf16*   Khi = Qlo + (size_t)BNC;
    __bf16*   Klo = Khi + (size_t)BNC;
    _Float16* Vt  = (_Float16*)(Klo + (size_t)BNC);
    _Float16* Xhi = Vt + (size_t)BNC;
    _Float16* Xlo = Xhi + (size_t)BNC;
    _Float16* Whi = Xlo + (size_t)BNC;
    _Float16* Wlo = Whi + (size_t)WELEMS;

    wtrans_kernel<<<dim3(WELEMS / 256), 256, 0, stream>>>(w1, w2, w3, Whi, Wlo);

    xsplit_kernel<<<dim3(HH, CCH / 64, BATCH), 256, 0, stream>>>(X, Xhi, Xlo);

    conv_mfma_kernel<<<dim3(HH / 2, BATCH, 3), 512, 0, stream>>>(
        Xhi, Xlo, Whi, Wlo, b1, b2, b3, Qhi, Qlo, Khi, Klo, Dws);

    transpose_v_kernel<<<dim3(NN / 64, CCH / 64, BATCH), 256, 0, stream>>>(Dws, Vt);

    // dynamic LDS: K chunk hi/lo 32 KB + V 64 KB + P 34 KB = 133120 B
    attn_mfma_kernel<<<dim3(256), 256, 133120, stream>>>(
        Qhi, Qlo, Khi, Klo, Vt, alpha, out);
}